// Round 4
// baseline (290.076 us; speedup 1.0000x reference)
//
#include <hip/hip_runtime.h>

#define HW 250   // spatial size
// 8 batches * 32*32 windows = 8192 blocks; 64 tokens/window, C=28, NH=4, HD=7

typedef float    f32x16 __attribute__((ext_vector_type(16)));
typedef _Float16 f16x8  __attribute__((ext_vector_type(8)));
typedef __fp16   fp16x2 __attribute__((ext_vector_type(2)));

union FragU { unsigned u[4]; f16x8 f; };

__device__ inline unsigned pkrtz(float a, float b) {
    union { fp16x2 h; unsigned u; } c;
    c.h = __builtin_amdgcn_cvt_pkrtz(a, b);
    return c.u;
}

__global__ __launch_bounds__(256, 4)
void win_attn(const float* __restrict__ x,
              const float* __restrict__ qkv_w,
              const float* __restrict__ qkv_b,
              const float* __restrict__ proj_w,
              const float* __restrict__ proj_b,
              float* __restrict__ out)
{
    // LDS: 8K + 9.19K + 3.06K + 4K + 7.22K + 0.45K = 32.6 KB -> 4 blocks/CU
    __shared__ __align__(16) float xs[64 * 32];     // x window, float4-group XOR swizzle
    __shared__ __align__(16) float s_w[84 * 28];    // qkv weights
    __shared__ __align__(16) float s_pw[28 * 28];   // proj weights
    __shared__ __align__(16) short s_vt[4 * 512];   // V^T f16 [h][d(8)][tok 64], XOR swz
    __shared__ __align__(16) float s_oT[28 * 66];   // attention out, transposed [c][q]
    __shared__ float s_qb[84];
    __shared__ float s_pb[28];

    const int t    = threadIdx.x;
    const int lane = t & 63;
    const int w    = t >> 6;          // wave = head
    const int s_   = lane >> 5;       // half-wave
    const int col  = lane & 31;
    const int blk = blockIdx.x;
    const int b   = blk >> 10;
    const int p   = blk & 1023;
    const int r0  = (p >> 5) << 3;
    const int c0  = (p & 31) << 3;

    // ---------------- P0: stage weights + x window ----------------
    for (int i = t; i < 588; i += 256)
        *(float4*)&s_w[i * 4] = *(const float4*)&qkv_w[i * 4];
    for (int i = t; i < 196; i += 256)
        *(float4*)&s_pw[i * 4] = *(const float4*)&proj_w[i * 4];
    if (t < 84) s_qb[t] = qkv_b[t];
    if (t < 28) s_pb[t] = proj_b[t];

    #pragma unroll
    for (int it = 0; it < 2; ++it) {
        const int i = t + it * 256;        // 64 rows x 8 groups (group 7 idle)
        const int n = i >> 3, g = i & 7;
        if (g < 7) {
            const int r = r0 + (n >> 3), c = c0 + (n & 7);
            float4 v = make_float4(0.f, 0.f, 0.f, 0.f);
            if (r < HW && c < HW)
                v = *(const float4*)&x[((b * HW + r) * HW + c) * 28 + g * 4];
            *(float4*)&xs[n * 32 + ((g ^ (n & 7)) << 2)] = v;
        }
    }
    __syncthreads();

    // ---------------- P1: per-head qkv (thread = token, wave = head) ----------------
    FragU qf[2], kf[2];
    {
        const int n = lane;
        float xr[28];
        #pragma unroll
        for (int g = 0; g < 7; ++g) {
            const float4 v = *(const float4*)&xs[n * 32 + ((g ^ (n & 7)) << 2)];
            xr[g*4+0] = v.x; xr[g*4+1] = v.y; xr[g*4+2] = v.z; xr[g*4+3] = v.w;
        }
        float qd[7], kd[7], vd[7];
        #pragma unroll
        for (int which = 0; which < 3; ++which) {   // 0=q 1=k 2=v
            float* dst = (which == 0) ? qd : (which == 1) ? kd : vd;
            const int rbase = which * 28 + w * 7;
            #pragma unroll
            for (int d = 0; d < 7; ++d) {
                const float* wr = &s_w[(rbase + d) * 28];
                float acc = s_qb[rbase + d];
                #pragma unroll
                for (int g = 0; g < 7; ++g) {
                    const float4 ww = *(const float4*)&wr[g * 4];
                    acc += xr[g*4+0]*ww.x + xr[g*4+1]*ww.y + xr[g*4+2]*ww.z + xr[g*4+3]*ww.w;
                }
                dst[d] = acc;
            }
        }
        // V -> LDS transposed f16, XOR-swizzled: elem = w*512 + ((d*64 + n) ^ (d<<3))
        #pragma unroll
        for (int d = 0; d < 7; ++d) {
            const unsigned hv = pkrtz(vd[d], 0.f);
            s_vt[w * 512 + ((d * 64 + n) ^ (d << 3))] = (short)(hv & 0xffff);
        }
        // Q/K fragments in-register (K=16, dims 7..15 zero)
        const float SC = 0.37796447300922725f * 1.4426950408889634f; // 7^-0.5 * log2e
        unsigned qp[4] = { pkrtz(qd[0]*SC, qd[1]*SC), pkrtz(qd[2]*SC, qd[3]*SC),
                           pkrtz(qd[4]*SC, qd[5]*SC), pkrtz(qd[6]*SC, 0.f) };
        unsigned kp[4] = { pkrtz(kd[0], kd[1]), pkrtz(kd[2], kd[3]),
                           pkrtz(kd[4], kd[5]), pkrtz(kd[6], 0.f) };
        #pragma unroll
        for (int j = 0; j < 4; ++j) {
            const unsigned qsw = (unsigned)__shfl_xor((int)qp[j], 32);
            const unsigned ksw = (unsigned)__shfl_xor((int)kp[j], 32);
            qf[0].u[j] = s_ ? 0u : qp[j];   // B-frag, q-tokens 0-31 (upper k-half zero)
            qf[1].u[j] = s_ ? 0u : qsw;     // q-tokens 32-63
            kf[0].u[j] = s_ ? 0u : kp[j];   // A-frag, k-tokens 0-31
            kf[1].u[j] = s_ ? 0u : ksw;
        }
    }

    // ---------------- P2: attention via MFMA (S^T = K·Q^T, O^T = V^T·P^T) ----------------
    {
        const int vr = min(8, HW - r0), vc = min(8, HW - c0);
        const bool edge = (vr < 8) || (vc < 8);
        const int dd = (col < 7) ? col : 6;   // V^T row (clamped; rows 7-31 unused)

        #pragma unroll
        for (int qt = 0; qt < 2; ++qt) {
            f32x16 a0, a1;
            #pragma unroll
            for (int r = 0; r < 16; ++r) { a0[r] = 0.f; a1[r] = 0.f; }
            a0 = __builtin_amdgcn_mfma_f32_32x32x16_f16(kf[0].f, qf[qt].f, a0, 0, 0, 0);
            a1 = __builtin_amdgcn_mfma_f32_32x32x16_f16(kf[1].f, qf[qt].f, a1, 0, 0, 0);
            // S^T layout: value r of tile kt -> k-token 32kt + (r&3) + 8(r>>2) + 4s_,
            //             column -> q-token 32qt + col
            if (edge) {
                #pragma unroll
                for (int r = 0; r < 16; ++r) {
                    const int kc  = (r & 3) + 4 * s_;
                    const int kr0 = (r >> 2), kr1 = 4 + (r >> 2);
                    a0[r] = (kr0 < vr && kc < vc) ? a0[r] : -1e30f;
                    a1[r] = (kr1 < vr && kc < vc) ? a1[r] : -1e30f;
                }
            }
            // softmax over k (32 local values + partner half-wave)
            float m = -1e30f;
            #pragma unroll
            for (int r = 0; r < 16; ++r) { m = fmaxf(m, a0[r]); m = fmaxf(m, a1[r]); }
            m = fmaxf(m, __shfl_xor(m, 32));
            float sum = 0.f;
            #pragma unroll
            for (int r = 0; r < 16; ++r) {
                a0[r] = __builtin_amdgcn_exp2f(a0[r] - m); sum += a0[r];
                a1[r] = __builtin_amdgcn_exp2f(a1[r] - m); sum += a1[r];
            }
            sum += __shfl_xor(sum, 32);
            const float inv = __builtin_amdgcn_rcpf(sum);

            f32x16 O;
            #pragma unroll
            for (int r = 0; r < 16; ++r) O[r] = 0.f;
            #pragma unroll
            for (int tt = 0; tt < 4; ++tt) {
                // A-frag: V^T f16 [dd][16tt + 8s_ .. +7]
                const f16x8 vfrag = *(const f16x8*)&s_vt[w * 512 + ((dd * 64 + 16 * tt + 8 * s_) ^ (dd << 3))];
                // B-frag: P^T slice; own pairs + partner half-wave pairs
                const int bb = 8 * (tt & 1);
                float p0,p1,p2,p3,p4,p5,p6,p7;
                if (tt < 2) { p0=a0[bb+0];p1=a0[bb+1];p2=a0[bb+2];p3=a0[bb+3];
                              p4=a0[bb+4];p5=a0[bb+5];p6=a0[bb+6];p7=a0[bb+7]; }
                else        { p0=a1[bb+0];p1=a1[bb+1];p2=a1[bb+2];p3=a1[bb+3];
                              p4=a1[bb+4];p5=a1[bb+5];p6=a1[bb+6];p7=a1[bb+7]; }
                const unsigned X0 = pkrtz(p0, p1), X1 = pkrtz(p2, p3);
                const unsigned Y0 = pkrtz(p4, p5), Y1 = pkrtz(p6, p7);
                const unsigned sX0 = (unsigned)__shfl_xor((int)X0, 32);
                const unsigned sX1 = (unsigned)__shfl_xor((int)X1, 32);
                const unsigned sY0 = (unsigned)__shfl_xor((int)Y0, 32);
                const unsigned sY1 = (unsigned)__shfl_xor((int)Y1, 32);
                FragU pf;
                pf.u[0] = s_ ? sY0 : X0;
                pf.u[1] = s_ ? sY1 : X1;
                pf.u[2] = s_ ? Y0  : sX0;
                pf.u[3] = s_ ? Y1  : sX1;
                O = __builtin_amdgcn_mfma_f32_32x32x16_f16(vfrag, pf.f, O, 0, 0, 0);
            }
            // O^T: reg r (0..3) -> d = r + 4s_ (d=7 dead), column q = 32qt + col
            #pragma unroll
            for (int r = 0; r < 4; ++r) {
                const int d = r + 4 * s_;
                if (d < 7) s_oT[(w * 7 + d) * 66 + 32 * qt + col] = O[r] * inv;
            }
        }
    }
    __syncthreads();

    // ---------------- P3: output projection + cropped write ----------------
    {
        const int n = t >> 2, q4 = t & 3;
        const int r = r0 + (n >> 3), c = c0 + (n & 7);
        if (r < HW && c < HW) {
            float xr[28];
            #pragma unroll
            for (int cc = 0; cc < 28; ++cc) xr[cc] = s_oT[cc * 66 + n];
            float* dst = &out[((b * HW + r) * HW + c) * 28 + q4 * 7];
            #pragma unroll
            for (int j = 0; j < 7; ++j) {
                const int co = q4 * 7 + j;
                const float* wr = &s_pw[co * 28];
                float acc = s_pb[co];
                #pragma unroll
                for (int g = 0; g < 7; ++g) {
                    const float4 ww = *(const float4*)&wr[g * 4];
                    acc += xr[g*4+0]*ww.x + xr[g*4+1]*ww.y + xr[g*4+2]*ww.z + xr[g*4+3]*ww.w;
                }
                dst[j] = acc;
            }
        }
    }
}

extern "C" void kernel_launch(void* const* d_in, const int* in_sizes, int n_in,
                              void* d_out, int out_size, void* d_ws, size_t ws_size,
                              hipStream_t stream) {
    const float* x      = (const float*)d_in[0];
    const float* qkv_w  = (const float*)d_in[1];
    const float* qkv_b  = (const float*)d_in[2];
    const float* proj_w = (const float*)d_in[3];
    const float* proj_b = (const float*)d_in[4];
    // inputs 5..18 (DynamicPosBias MLP): PDIM==1 makes every layernorm collapse to
    // its bias -> the bias table is a per-head constant -> cancelled by softmax.
    float* out = (float*)d_out;

    dim3 grid(8 * 32 * 32);
    dim3 block(256);
    hipLaunchKernelGGL(win_attn, grid, block, 0, stream,
                       x, qkv_w, qkv_b, proj_w, proj_b, out);
}

// Round 5
// 104.789 us; speedup vs baseline: 2.7682x; 2.7682x over previous
//
#include <hip/hip_runtime.h>

#define HW 250   // spatial size
// 8 batches * 32*32 windows = 8192 blocks; 64 tokens/window, C=28, NH=4, HD=7

typedef float    f32x16 __attribute__((ext_vector_type(16)));
typedef _Float16 f16x8  __attribute__((ext_vector_type(8)));
typedef unsigned u32x4  __attribute__((ext_vector_type(4)));

__device__ inline unsigned pkrtz(float a, float b) {
    return __builtin_bit_cast(unsigned, __builtin_amdgcn_cvt_pkrtz(a, b));
}
__device__ inline f16x8 as_f16x8(u32x4 v) { return __builtin_bit_cast(f16x8, v); }

__global__ __launch_bounds__(256, 4)
void win_attn(const float* __restrict__ x,
              const float* __restrict__ qkv_w,
              const float* __restrict__ qkv_b,
              const float* __restrict__ proj_w,
              const float* __restrict__ proj_b,
              float* __restrict__ out)
{
    // LDS: 8K + 9.19K + 3.06K + 4K + 7.22K + 0.45K = 32.6 KB -> 4 blocks/CU
    __shared__ __align__(16) float xs[64 * 32];     // x window, float4-group XOR swizzle
    __shared__ __align__(16) float s_w[84 * 28];    // qkv weights
    __shared__ __align__(16) float s_pw[28 * 28];   // proj weights
    __shared__ __align__(16) short s_vt[4 * 512];   // V^T f16 [h][d(8)][tok 64], XOR swz
    __shared__ __align__(16) float s_oT[28 * 66];   // attention out, transposed [c][q]
    __shared__ float s_qb[84];
    __shared__ float s_pb[28];

    const int t    = threadIdx.x;
    const int lane = t & 63;
    const int w    = t >> 6;          // wave = head
    const int s_   = lane >> 5;       // half-wave
    const int col  = lane & 31;
    const int blk = blockIdx.x;
    const int b   = blk >> 10;
    const int p   = blk & 1023;
    const int r0  = (p >> 5) << 3;
    const int c0  = (p & 31) << 3;

    // ---------------- P0: stage weights + x window ----------------
    for (int i = t; i < 588; i += 256)
        *(float4*)&s_w[i * 4] = *(const float4*)&qkv_w[i * 4];
    for (int i = t; i < 196; i += 256)
        *(float4*)&s_pw[i * 4] = *(const float4*)&proj_w[i * 4];
    if (t < 84) s_qb[t] = qkv_b[t];
    if (t < 28) s_pb[t] = proj_b[t];

    #pragma unroll
    for (int it = 0; it < 2; ++it) {
        const int i = t + it * 256;        // 64 rows x 8 groups (group 7 idle)
        const int n = i >> 3, g = i & 7;
        if (g < 7) {
            const int r = r0 + (n >> 3), c = c0 + (n & 7);
            float4 v = make_float4(0.f, 0.f, 0.f, 0.f);
            if (r < HW && c < HW)
                v = *(const float4*)&x[((b * HW + r) * HW + c) * 28 + g * 4];
            *(float4*)&xs[n * 32 + ((g ^ (n & 7)) << 2)] = v;
        }
    }
    __syncthreads();

    // ---------------- P1: per-head qkv (thread = token, wave = head) ----------------
    u32x4 qf0, qf1, kf0, kf1;
    {
        const int n = lane;
        float xr[28];
        #pragma unroll
        for (int g = 0; g < 7; ++g) {
            const float4 v = *(const float4*)&xs[n * 32 + ((g ^ (n & 7)) << 2)];
            xr[g*4+0] = v.x; xr[g*4+1] = v.y; xr[g*4+2] = v.z; xr[g*4+3] = v.w;
        }
        float qd[7], kd[7], vd[7];
        #pragma unroll
        for (int d = 0; d < 7; ++d) {           // q
            const int ri = w * 7 + d;
            const float* wr = &s_w[ri * 28];
            float acc = s_qb[ri];
            #pragma unroll
            for (int g = 0; g < 7; ++g) {
                const float4 ww = *(const float4*)&wr[g * 4];
                acc += xr[g*4+0]*ww.x + xr[g*4+1]*ww.y + xr[g*4+2]*ww.z + xr[g*4+3]*ww.w;
            }
            qd[d] = acc;
        }
        #pragma unroll
        for (int d = 0; d < 7; ++d) {           // k
            const int ri = 28 + w * 7 + d;
            const float* wr = &s_w[ri * 28];
            float acc = s_qb[ri];
            #pragma unroll
            for (int g = 0; g < 7; ++g) {
                const float4 ww = *(const float4*)&wr[g * 4];
                acc += xr[g*4+0]*ww.x + xr[g*4+1]*ww.y + xr[g*4+2]*ww.z + xr[g*4+3]*ww.w;
            }
            kd[d] = acc;
        }
        #pragma unroll
        for (int d = 0; d < 7; ++d) {           // v
            const int ri = 56 + w * 7 + d;
            const float* wr = &s_w[ri * 28];
            float acc = s_qb[ri];
            #pragma unroll
            for (int g = 0; g < 7; ++g) {
                const float4 ww = *(const float4*)&wr[g * 4];
                acc += xr[g*4+0]*ww.x + xr[g*4+1]*ww.y + xr[g*4+2]*ww.z + xr[g*4+3]*ww.w;
            }
            vd[d] = acc;
        }
        // V -> LDS transposed f16, XOR-swizzled: elem = w*512 + ((d*64 + n) ^ (d<<3))
        #pragma unroll
        for (int d = 0; d < 7; ++d) {
            const unsigned hv = pkrtz(vd[d], 0.f);
            s_vt[w * 512 + ((d * 64 + n) ^ (d << 3))] = (short)(hv & 0xffff);
        }
        // Q/K fragments in-register (K=16, dims 7..15 zero)
        const float SC = 0.37796447300922725f * 1.4426950408889634f; // 7^-0.5 * log2e
        const unsigned qp0 = pkrtz(qd[0]*SC, qd[1]*SC), qp1 = pkrtz(qd[2]*SC, qd[3]*SC),
                       qp2 = pkrtz(qd[4]*SC, qd[5]*SC), qp3 = pkrtz(qd[6]*SC, 0.f);
        const unsigned kp0 = pkrtz(kd[0], kd[1]), kp1 = pkrtz(kd[2], kd[3]),
                       kp2 = pkrtz(kd[4], kd[5]), kp3 = pkrtz(kd[6], 0.f);
        const unsigned qs0 = (unsigned)__shfl_xor((int)qp0, 32),
                       qs1 = (unsigned)__shfl_xor((int)qp1, 32),
                       qs2 = (unsigned)__shfl_xor((int)qp2, 32),
                       qs3 = (unsigned)__shfl_xor((int)qp3, 32);
        const unsigned ks0 = (unsigned)__shfl_xor((int)kp0, 32),
                       ks1 = (unsigned)__shfl_xor((int)kp1, 32),
                       ks2 = (unsigned)__shfl_xor((int)kp2, 32),
                       ks3 = (unsigned)__shfl_xor((int)kp3, 32);
        qf0.x = s_ ? 0u : qp0; qf0.y = s_ ? 0u : qp1; qf0.z = s_ ? 0u : qp2; qf0.w = s_ ? 0u : qp3;
        qf1.x = s_ ? 0u : qs0; qf1.y = s_ ? 0u : qs1; qf1.z = s_ ? 0u : qs2; qf1.w = s_ ? 0u : qs3;
        kf0.x = s_ ? 0u : kp0; kf0.y = s_ ? 0u : kp1; kf0.z = s_ ? 0u : kp2; kf0.w = s_ ? 0u : kp3;
        kf1.x = s_ ? 0u : ks0; kf1.y = s_ ? 0u : ks1; kf1.z = s_ ? 0u : ks2; kf1.w = s_ ? 0u : ks3;
    }

    // ---------------- P2: attention via MFMA (S^T = K·Q^T, O^T = V^T·P^T) ----------------
    {
        const int vr = min(8, HW - r0), vc = min(8, HW - c0);
        const bool edge = (vr < 8) || (vc < 8);
        const int dd = (col < 7) ? col : 6;   // V^T row (clamped; rows 7-31 unused)
        const f16x8 kfa = as_f16x8(kf0), kfb = as_f16x8(kf1);

        #pragma unroll
        for (int qt = 0; qt < 2; ++qt) {
            const f16x8 qfrag = as_f16x8(qt == 0 ? qf0 : qf1);
            f32x16 a0, a1;
            #pragma unroll
            for (int r = 0; r < 16; ++r) { a0[r] = 0.f; a1[r] = 0.f; }
            a0 = __builtin_amdgcn_mfma_f32_32x32x16_f16(kfa, qfrag, a0, 0, 0, 0);
            a1 = __builtin_amdgcn_mfma_f32_32x32x16_f16(kfb, qfrag, a1, 0, 0, 0);
            // S^T: reg r of tile kt -> k-token 32kt + (r&3) + 8(r>>2) + 4s_, col -> q-token
            if (edge) {
                #pragma unroll
                for (int r = 0; r < 16; ++r) {
                    const int kc  = (r & 3) + 4 * s_;
                    const int kr0 = (r >> 2), kr1 = 4 + (r >> 2);
                    a0[r] = (kr0 < vr && kc < vc) ? a0[r] : -1e30f;
                    a1[r] = (kr1 < vr && kc < vc) ? a1[r] : -1e30f;
                }
            }
            // softmax over k (32 local values + partner half-wave)
            float m = -1e30f;
            #pragma unroll
            for (int r = 0; r < 16; ++r) { m = fmaxf(m, a0[r]); m = fmaxf(m, a1[r]); }
            m = fmaxf(m, __shfl_xor(m, 32));
            float sum = 0.f;
            #pragma unroll
            for (int r = 0; r < 16; ++r) {
                a0[r] = __builtin_amdgcn_exp2f(a0[r] - m); sum += a0[r];
                a1[r] = __builtin_amdgcn_exp2f(a1[r] - m); sum += a1[r];
            }
            sum += __shfl_xor(sum, 32);
            const float inv = __builtin_amdgcn_rcpf(sum);

            f32x16 O;
            #pragma unroll
            for (int r = 0; r < 16; ++r) O[r] = 0.f;
            #pragma unroll
            for (int tt = 0; tt < 4; ++tt) {
                // A-frag: V^T f16 [dd][16tt + 8s_ .. +7]
                const f16x8 vfrag = *(const f16x8*)&s_vt[w * 512 + ((dd * 64 + 16 * tt + 8 * s_) ^ (dd << 3))];
                // B-frag: P^T slice; own pairs + partner half-wave pairs
                const int bb = 8 * (tt & 1);
                float p0,p1,p2,p3,p4,p5,p6,p7;
                if (tt < 2) { p0=a0[bb+0];p1=a0[bb+1];p2=a0[bb+2];p3=a0[bb+3];
                              p4=a0[bb+4];p5=a0[bb+5];p6=a0[bb+6];p7=a0[bb+7]; }
                else        { p0=a1[bb+0];p1=a1[bb+1];p2=a1[bb+2];p3=a1[bb+3];
                              p4=a1[bb+4];p5=a1[bb+5];p6=a1[bb+6];p7=a1[bb+7]; }
                const unsigned X0 = pkrtz(p0, p1), X1 = pkrtz(p2, p3);
                const unsigned Y0 = pkrtz(p4, p5), Y1 = pkrtz(p6, p7);
                const unsigned sX0 = (unsigned)__shfl_xor((int)X0, 32);
                const unsigned sX1 = (unsigned)__shfl_xor((int)X1, 32);
                const unsigned sY0 = (unsigned)__shfl_xor((int)Y0, 32);
                const unsigned sY1 = (unsigned)__shfl_xor((int)Y1, 32);
                u32x4 pf;
                pf.x = s_ ? sY0 : X0;
                pf.y = s_ ? sY1 : X1;
                pf.z = s_ ? Y0  : sX0;
                pf.w = s_ ? Y1  : sX1;
                O = __builtin_amdgcn_mfma_f32_32x32x16_f16(vfrag, as_f16x8(pf), O, 0, 0, 0);
            }
            // O^T: reg r (0..3) -> d = r + 4s_ (d=7 dead), column q = 32qt + col
            #pragma unroll
            for (int r = 0; r < 4; ++r) {
                const int d = r + 4 * s_;
                if (d < 7) s_oT[(w * 7 + d) * 66 + 32 * qt + col] = O[r] * inv;
            }
        }
    }
    __syncthreads();

    // ---------------- P3: output projection + cropped write ----------------
    {
        const int n = t >> 2, q4 = t & 3;
        const int r = r0 + (n >> 3), c = c0 + (n & 7);
        if (r < HW && c < HW) {
            float xr[28];
            #pragma unroll
            for (int cc = 0; cc < 28; ++cc) xr[cc] = s_oT[cc * 66 + n];
            float* dst = &out[((b * HW + r) * HW + c) * 28 + q4 * 7];
            #pragma unroll
            for (int j = 0; j < 7; ++j) {
                const int co = q4 * 7 + j;
                const float* wr = &s_pw[co * 28];
                float acc = s_pb[co];
                #pragma unroll
                for (int g = 0; g < 7; ++g) {
                    const float4 ww = *(const float4*)&wr[g * 4];
                    acc += xr[g*4+0]*ww.x + xr[g*4+1]*ww.y + xr[g*4+2]*ww.z + xr[g*4+3]*ww.w;
                }
                dst[j] = acc;
            }
        }
    }
}

extern "C" void kernel_launch(void* const* d_in, const int* in_sizes, int n_in,
                              void* d_out, int out_size, void* d_ws, size_t ws_size,
                              hipStream_t stream) {
    const float* x      = (const float*)d_in[0];
    const float* qkv_w  = (const float*)d_in[1];
    const float* qkv_b  = (const float*)d_in[2];
    const float* proj_w = (const float*)d_in[3];
    const float* proj_b = (const float*)d_in[4];
    // inputs 5..18 (DynamicPosBias MLP): PDIM==1 makes every layernorm collapse to
    // its bias -> the bias table is a per-head constant -> cancelled by softmax.
    float* out = (float*)d_out;

    dim3 grid(8 * 32 * 32);
    dim3 block(256);
    hipLaunchKernelGGL(win_attn, grid, block, 0, stream,
                       x, qkv_w, qkv_b, proj_w, proj_b, out);
}

// Round 6
// 63.393 us; speedup vs baseline: 4.5758x; 1.6530x over previous
//
#include <hip/hip_runtime.h>

#define HW 250   // spatial size
// 8 batches * 32*32 windows = 8192 blocks; 64 tokens/window, C=28, NH=4, HD=7

typedef float    f32x16 __attribute__((ext_vector_type(16)));
typedef _Float16 f16x8  __attribute__((ext_vector_type(8)));
typedef unsigned u32x4  __attribute__((ext_vector_type(4)));

__device__ inline unsigned pkrtz(float a, float b) {
    return __builtin_bit_cast(unsigned, __builtin_amdgcn_cvt_pkrtz(a, b));
}
__device__ inline f16x8 as_f16x8(u32x4 v) { return __builtin_bit_cast(f16x8, v); }

__global__ __launch_bounds__(256, 4)
void win_attn(const float* __restrict__ x,
              const float* __restrict__ qkv_w,
              const float* __restrict__ qkv_b,
              const float* __restrict__ proj_w,
              const float* __restrict__ proj_b,
              float* __restrict__ out)
{
    // LDS: 5.0K + 10.0K + 3.06K + 4K + 7.22K + 0.11K = 30.1 KB
    __shared__ __align__(16) short s_x16[64 * 40];  // x f16 [tok][40]: ch0-27, slot28=1.0, 29-31=0
    __shared__ __align__(16) short s_wa[128 * 40];  // W f16 [head 4][arow 32][40]; arow: q0-6,_,k0-6,_,v0-6,_
    __shared__ __align__(16) float s_pw[28 * 28];   // proj weights f32
    __shared__ __align__(16) short s_vt[4 * 512];   // V^T f16 [h][d(8)][tok 64], XOR swz
    __shared__ __align__(16) float s_oT[28 * 66];   // attention out, transposed [c][q]
    __shared__ float s_pb[28];

    const int t    = threadIdx.x;
    const int lane = t & 63;
    const int w    = t >> 6;          // wave = head
    const int s_   = lane >> 5;       // half-wave
    const int col  = lane & 31;
    const int blk = blockIdx.x;
    const int b   = blk >> 10;
    const int p   = blk & 1023;
    const int r0  = (p >> 5) << 3;
    const int c0  = (p & 31) << 3;

    // ---------------- P0: stage proj w, x->f16, qkv W->f16 (permuted, q pre-scaled) ----------------
    for (int i = t; i < 196; i += 256)
        *(float4*)&s_pw[i * 4] = *(const float4*)&proj_w[i * 4];
    if (t < 28) s_pb[t] = proj_b[t];

    #pragma unroll
    for (int it = 0; it < 2; ++it) {
        const int i = t + it * 256;        // 64 rows x 8 groups
        const int n = i >> 3, g = i & 7;
        if (g < 7) {
            const int r = r0 + (n >> 3), c = c0 + (n & 7);
            float4 v = make_float4(0.f, 0.f, 0.f, 0.f);
            if (r < HW && c < HW)
                v = *(const float4*)&x[((b * HW + r) * HW + c) * 28 + g * 4];
            uint2 h; h.x = pkrtz(v.x, v.y); h.y = pkrtz(v.z, v.w);
            *(uint2*)&s_x16[n * 40 + g * 4] = h;
        } else {
            uint2 h; h.x = 0x00003C00u; h.y = 0u;   // slot28 = 1.0 (bias multiplicand)
            *(uint2*)&s_x16[n * 40 + 28] = h;
        }
    }

    {
        const int rowid = t >> 1, half = t & 1;    // 128 A-rows, 2 halves of 16 k-slots
        const int slab = rowid >> 5, a = rowid & 31;
        int src = -1; float sc = 1.f;
        if (a < 7)               { src = slab * 7 + a;              sc = 0.5452538663326288f; } // 7^-.5*log2e
        else if (a >= 8 && a < 15)  { src = 28 + slab * 7 + (a - 8);  }
        else if (a >= 16 && a < 23) { src = 56 + slab * 7 + (a - 16); }
        u32x4 o0 = {0u,0u,0u,0u}, o1 = {0u,0u,0u,0u};
        if (src >= 0) {
            const float* wr = &qkv_w[src * 28];
            if (half == 0) {
                const float4 A = *(const float4*)&wr[0],  B = *(const float4*)&wr[4];
                const float4 C = *(const float4*)&wr[8],  D = *(const float4*)&wr[12];
                o0.x = pkrtz(A.x*sc, A.y*sc); o0.y = pkrtz(A.z*sc, A.w*sc);
                o0.z = pkrtz(B.x*sc, B.y*sc); o0.w = pkrtz(B.z*sc, B.w*sc);
                o1.x = pkrtz(C.x*sc, C.y*sc); o1.y = pkrtz(C.z*sc, C.w*sc);
                o1.z = pkrtz(D.x*sc, D.y*sc); o1.w = pkrtz(D.z*sc, D.w*sc);
            } else {
                const float4 A = *(const float4*)&wr[16], B = *(const float4*)&wr[20];
                const float4 C = *(const float4*)&wr[24];
                const float bias = qkv_b[src];
                o0.x = pkrtz(A.x*sc, A.y*sc); o0.y = pkrtz(A.z*sc, A.w*sc);
                o0.z = pkrtz(B.x*sc, B.y*sc); o0.w = pkrtz(B.z*sc, B.w*sc);
                o1.x = pkrtz(C.x*sc, C.y*sc); o1.y = pkrtz(C.z*sc, C.w*sc);
                o1.z = pkrtz(bias*sc, 0.f);   o1.w = 0u;     // slot28 = bias, 29-31 = 0
            }
        }
        *(u32x4*)&s_wa[rowid * 40 + half * 16 + 0] = o0;
        *(u32x4*)&s_wa[rowid * 40 + half * 16 + 8] = o1;
    }
    __syncthreads();

    // ---------------- P1: qkv via MFMA; assemble attention frags ----------------
    u32x4 qf0, qf1, kf0, kf1;
    {
        const f16x8 wfa = *(const f16x8*)&s_wa[(w * 32 + col) * 40 + s_ * 8];       // k 0-15
        const f16x8 wfb = *(const f16x8*)&s_wa[(w * 32 + col) * 40 + 16 + s_ * 8];  // k 16-31
        #pragma unroll
        for (int tile = 0; tile < 2; ++tile) {
            const int tok = tile * 32 + col;
            const f16x8 xb0 = *(const f16x8*)&s_x16[tok * 40 + s_ * 8];
            const f16x8 xb1 = *(const f16x8*)&s_x16[tok * 40 + 16 + s_ * 8];
            f32x16 C;
            #pragma unroll
            for (int r = 0; r < 16; ++r) C[r] = 0.f;
            C = __builtin_amdgcn_mfma_f32_32x32x16_f16(wfa, xb0, C, 0, 0, 0);
            C = __builtin_amdgcn_mfma_f32_32x32x16_f16(wfb, xb1, C, 0, 0, 0);
            // lane's C rows: (r&3)+8*(r>>2)+4*s_ ; q rows 0-6, k rows 8-14, v rows 16-22
            // s0: regs0-3=q0-3, 4-7=k0-3, 8-11=v0-3 ; s1: regs0-3=q4-6+junk, 4-7=k4-6+junk, 8-11=v4-6,0
            const unsigned qA = pkrtz(C[0], C[1]);              // s0:q01  s1:q45
            const unsigned qB = pkrtz(C[2], s_ ? 0.f : C[3]);   // s0:q23  s1:q6,0
            const unsigned kA = pkrtz(C[4], C[5]);              // s0:k01  s1:k45
            const unsigned kB = pkrtz(C[6], s_ ? 0.f : C[7]);   // s0:k23  s1:k6,0
            const unsigned qAx = (unsigned)__shfl_xor((int)qA, 32);
            const unsigned qBx = (unsigned)__shfl_xor((int)qB, 32);
            const unsigned kAx = (unsigned)__shfl_xor((int)kA, 32);
            const unsigned kBx = (unsigned)__shfl_xor((int)kB, 32);
            u32x4 qf, kf;
            qf.x = s_ ? 0u : qA;  qf.y = s_ ? 0u : qB;
            qf.z = s_ ? 0u : qAx; qf.w = s_ ? 0u : qBx;
            kf.x = s_ ? 0u : kA;  kf.y = s_ ? 0u : kB;
            kf.z = s_ ? 0u : kAx; kf.w = s_ ? 0u : kBx;
            // V -> s_vt: lane's v-dims d = 4s_+j in regs 8-11 (d=7 skipped)
            #pragma unroll
            for (int j = 0; j < 4; ++j) {
                const int d = 4 * s_ + j;
                if (d < 7) {
                    const unsigned hv = pkrtz(C[8 + j], 0.f);
                    s_vt[w * 512 + ((d * 64 + tok) ^ (d << 3))] = (short)(hv & 0xffff);
                }
            }
            if (tile == 0) { qf0 = qf; kf0 = kf; } else { qf1 = qf; kf1 = kf; }
        }
    }
    __syncthreads();

    // ---------------- P2: attention via MFMA (S^T = K·Q^T, O^T = V^T·P^T) ----------------
    {
        const int vr = min(8, HW - r0), vc = min(8, HW - c0);
        const bool edge = (vr < 8) || (vc < 8);
        const int dd = (col < 7) ? col : 6;   // V^T row (clamped; rows 7-31 unused)
        const f16x8 kfa = as_f16x8(kf0), kfb = as_f16x8(kf1);

        #pragma unroll
        for (int qt = 0; qt < 2; ++qt) {
            const f16x8 qfrag = as_f16x8(qt == 0 ? qf0 : qf1);
            f32x16 a0, a1;
            #pragma unroll
            for (int r = 0; r < 16; ++r) { a0[r] = 0.f; a1[r] = 0.f; }
            a0 = __builtin_amdgcn_mfma_f32_32x32x16_f16(kfa, qfrag, a0, 0, 0, 0);
            a1 = __builtin_amdgcn_mfma_f32_32x32x16_f16(kfb, qfrag, a1, 0, 0, 0);
            // S^T: reg r of tile kt -> k-token 32kt + (r&3) + 8(r>>2) + 4s_, col -> q-token
            if (edge) {
                #pragma unroll
                for (int r = 0; r < 16; ++r) {
                    const int kc  = (r & 3) + 4 * s_;
                    const int kr0 = (r >> 2), kr1 = 4 + (r >> 2);
                    a0[r] = (kr0 < vr && kc < vc) ? a0[r] : -1e30f;
                    a1[r] = (kr1 < vr && kc < vc) ? a1[r] : -1e30f;
                }
            }
            float m = -1e30f;
            #pragma unroll
            for (int r = 0; r < 16; ++r) { m = fmaxf(m, a0[r]); m = fmaxf(m, a1[r]); }
            m = fmaxf(m, __shfl_xor(m, 32));
            float sum = 0.f;
            #pragma unroll
            for (int r = 0; r < 16; ++r) {
                a0[r] = __builtin_amdgcn_exp2f(a0[r] - m); sum += a0[r];
                a1[r] = __builtin_amdgcn_exp2f(a1[r] - m); sum += a1[r];
            }
            sum += __shfl_xor(sum, 32);
            const float inv = __builtin_amdgcn_rcpf(sum);

            f32x16 O;
            #pragma unroll
            for (int r = 0; r < 16; ++r) O[r] = 0.f;
            #pragma unroll
            for (int tt = 0; tt < 4; ++tt) {
                const f16x8 vfrag = *(const f16x8*)&s_vt[w * 512 + ((dd * 64 + 16 * tt + 8 * s_) ^ (dd << 3))];
                const int bb = 8 * (tt & 1);
                float p0,p1,p2,p3,p4,p5,p6,p7;
                if (tt < 2) { p0=a0[bb+0];p1=a0[bb+1];p2=a0[bb+2];p3=a0[bb+3];
                              p4=a0[bb+4];p5=a0[bb+5];p6=a0[bb+6];p7=a0[bb+7]; }
                else        { p0=a1[bb+0];p1=a1[bb+1];p2=a1[bb+2];p3=a1[bb+3];
                              p4=a1[bb+4];p5=a1[bb+5];p6=a1[bb+6];p7=a1[bb+7]; }
                const unsigned X0 = pkrtz(p0, p1), X1 = pkrtz(p2, p3);
                const unsigned Y0 = pkrtz(p4, p5), Y1 = pkrtz(p6, p7);
                const unsigned sX0 = (unsigned)__shfl_xor((int)X0, 32);
                const unsigned sX1 = (unsigned)__shfl_xor((int)X1, 32);
                const unsigned sY0 = (unsigned)__shfl_xor((int)Y0, 32);
                const unsigned sY1 = (unsigned)__shfl_xor((int)Y1, 32);
                u32x4 pf;
                pf.x = s_ ? sY0 : X0;
                pf.y = s_ ? sY1 : X1;
                pf.z = s_ ? Y0  : sX0;
                pf.w = s_ ? Y1  : sX1;
                O = __builtin_amdgcn_mfma_f32_32x32x16_f16(vfrag, as_f16x8(pf), O, 0, 0, 0);
            }
            #pragma unroll
            for (int r = 0; r < 4; ++r) {
                const int d = r + 4 * s_;
                if (d < 7) s_oT[(w * 7 + d) * 66 + 32 * qt + col] = O[r] * inv;
            }
        }
    }
    __syncthreads();

    // ---------------- P3: output projection + cropped write ----------------
    {
        const int n = t >> 2, q4 = t & 3;
        const int r = r0 + (n >> 3), c = c0 + (n & 7);
        if (r < HW && c < HW) {
            float xr[28];
            #pragma unroll
            for (int cc = 0; cc < 28; ++cc) xr[cc] = s_oT[cc * 66 + n];
            float* dst = &out[((b * HW + r) * HW + c) * 28 + q4 * 7];
            #pragma unroll
            for (int j = 0; j < 7; ++j) {
                const int co = q4 * 7 + j;
                const float* wr = &s_pw[co * 28];
                float acc = s_pb[co];
                #pragma unroll
                for (int g = 0; g < 7; ++g) {
                    const float4 ww = *(const float4*)&wr[g * 4];
                    acc += xr[g*4+0]*ww.x + xr[g*4+1]*ww.y + xr[g*4+2]*ww.z + xr[g*4+3]*ww.w;
                }
                dst[j] = acc;
            }
        }
    }
}

extern "C" void kernel_launch(void* const* d_in, const int* in_sizes, int n_in,
                              void* d_out, int out_size, void* d_ws, size_t ws_size,
                              hipStream_t stream) {
    const float* x      = (const float*)d_in[0];
    const float* qkv_w  = (const float*)d_in[1];
    const float* qkv_b  = (const float*)d_in[2];
    const float* proj_w = (const float*)d_in[3];
    const float* proj_b = (const float*)d_in[4];
    // inputs 5..18 (DynamicPosBias MLP): PDIM==1 makes every layernorm collapse to
    // its bias -> the bias table is a per-head constant -> cancelled by softmax.
    float* out = (float*)d_out;

    dim3 grid(8 * 32 * 32);
    dim3 block(256);
    hipLaunchKernelGGL(win_attn, grid, block, 0, stream,
                       x, qkv_w, qkv_b, proj_w, proj_b, out);
}

// Round 8
// 58.257 us; speedup vs baseline: 4.9793x; 1.0882x over previous
//
#include <hip/hip_runtime.h>

#define HW 250   // spatial size
// 8 batches * 32*32 windows = 8192 blocks; 64 tokens/window, C=28, NH=4, HD=7

typedef float    f32x16 __attribute__((ext_vector_type(16)));
typedef _Float16 f16x8  __attribute__((ext_vector_type(8)));
typedef unsigned u32x4  __attribute__((ext_vector_type(4)));

__device__ inline unsigned pkrtz(float a, float b) {
    return __builtin_bit_cast(unsigned, __builtin_amdgcn_cvt_pkrtz(a, b));
}
__device__ inline f16x8 as_f16x8(u32x4 v) { return __builtin_bit_cast(f16x8, v); }

// LDS pool (shorts), all regions 16B-aligned, stride-40 rows (80 B -> aligned b128):
//   [0,2560)        s_x16 [64][40]  x f16: ch0-27, slot28=1.0, 29-31=0; ALIASED as s_o16 after P1
//   [2560,7680)     s_wa  [128][40] qkv W f16 (permuted rows, q pre-scaled)
//   [7680,8960)     s_pw16[32][40]  proj W f16, rows/k >=28 zero
//   [8960,11008)    s_vt  [4][512]  V^T f16 [h][d(8)][tok64], XOR swizzle
#define OFF_X   0
#define OFF_WA  2560
#define OFF_PW  7680
#define OFF_VT  8960

__global__ __launch_bounds__(256, 7)
void win_attn(const float* __restrict__ x,
              const float* __restrict__ qkv_w,
              const float* __restrict__ qkv_b,
              const float* __restrict__ proj_w,
              const float* __restrict__ proj_b,
              float* __restrict__ out)
{
    __shared__ __align__(16) short s_pool[11008];   // 21.5 KB
    __shared__ __align__(16) float s_pb[28];
    short* const s_x16  = s_pool + OFF_X;
    short* const s_wa   = s_pool + OFF_WA;
    short* const s_pw16 = s_pool + OFF_PW;
    short* const s_vt   = s_pool + OFF_VT;
    short* const s_o16  = s_pool + OFF_X;           // alias (x dead after P1 barrier)

    const int t    = threadIdx.x;
    const int lane = t & 63;
    const int w    = t >> 6;          // wave = head
    const int s_   = lane >> 5;       // half-wave
    const int col  = lane & 31;
    const int blk = blockIdx.x;
    const int b   = blk >> 10;
    const int p   = blk & 1023;
    const int r0  = (p >> 5) << 3;
    const int c0  = (p & 31) << 3;

    // ---------------- P0: stage proj W (f16), bias, x (f16), qkv W (f16 permuted) ----------------
    {
        const int co = t >> 3, g = t & 7;      // 32 rows x 8 groups
        uint2 h; h.x = 0u; h.y = 0u;
        if (g < 7) {
            if (co < 28) {
                const float4 v = *(const float4*)&proj_w[co * 28 + g * 4];
                h.x = pkrtz(v.x, v.y); h.y = pkrtz(v.z, v.w);
            }
            *(uint2*)&s_pw16[co * 40 + g * 4] = h;
        } else {
            *(uint2*)&s_pw16[co * 40 + 28] = h;    // k-slots 28-31 = 0
        }
    }
    if (t < 28) s_pb[t] = proj_b[t];

    #pragma unroll
    for (int it = 0; it < 2; ++it) {
        const int i = t + it * 256;        // 64 rows x 8 groups
        const int n = i >> 3, g = i & 7;
        if (g < 7) {
            const int r = r0 + (n >> 3), c = c0 + (n & 7);
            float4 v = make_float4(0.f, 0.f, 0.f, 0.f);
            if (r < HW && c < HW)
                v = *(const float4*)&x[((b * HW + r) * HW + c) * 28 + g * 4];
            uint2 h; h.x = pkrtz(v.x, v.y); h.y = pkrtz(v.z, v.w);
            *(uint2*)&s_x16[n * 40 + g * 4] = h;
        } else {
            uint2 h; h.x = 0x00003C00u; h.y = 0u;   // slot28 = 1.0 (bias multiplicand), 29-31 = 0
            *(uint2*)&s_x16[n * 40 + 28] = h;
        }
    }

    {
        const int rowid = t >> 1, half = t & 1;    // 128 A-rows, 2 halves of 16 k-slots
        const int slab = rowid >> 5, a = rowid & 31;
        int src = -1; float sc = 1.f;
        if (a < 7)               { src = slab * 7 + a;              sc = 0.5452538663326288f; } // 7^-.5*log2e
        else if (a >= 8 && a < 15)  { src = 28 + slab * 7 + (a - 8);  }
        else if (a >= 16 && a < 23) { src = 56 + slab * 7 + (a - 16); }
        u32x4 o0 = {0u,0u,0u,0u}, o1 = {0u,0u,0u,0u};
        if (src >= 0) {
            const float* wr = &qkv_w[src * 28];
            if (half == 0) {
                const float4 A = *(const float4*)&wr[0],  B = *(const float4*)&wr[4];
                const float4 C = *(const float4*)&wr[8],  D = *(const float4*)&wr[12];
                o0.x = pkrtz(A.x*sc, A.y*sc); o0.y = pkrtz(A.z*sc, A.w*sc);
                o0.z = pkrtz(B.x*sc, B.y*sc); o0.w = pkrtz(B.z*sc, B.w*sc);
                o1.x = pkrtz(C.x*sc, C.y*sc); o1.y = pkrtz(C.z*sc, C.w*sc);
                o1.z = pkrtz(D.x*sc, D.y*sc); o1.w = pkrtz(D.z*sc, D.w*sc);
            } else {
                const float4 A = *(const float4*)&wr[16], B = *(const float4*)&wr[20];
                const float4 C = *(const float4*)&wr[24];
                const float bias = qkv_b[src];
                o0.x = pkrtz(A.x*sc, A.y*sc); o0.y = pkrtz(A.z*sc, A.w*sc);
                o0.z = pkrtz(B.x*sc, B.y*sc); o0.w = pkrtz(B.z*sc, B.w*sc);
                o1.x = pkrtz(C.x*sc, C.y*sc); o1.y = pkrtz(C.z*sc, C.w*sc);
                o1.z = pkrtz(bias*sc, 0.f);   o1.w = 0u;     // slot28 = bias, 29-31 = 0
            }
        }
        *(u32x4*)&s_wa[rowid * 40 + half * 16 + 0] = o0;
        *(u32x4*)&s_wa[rowid * 40 + half * 16 + 8] = o1;
    }
    __syncthreads();

    // ---------------- P1: qkv via MFMA; assemble attention frags ----------------
    u32x4 qf0, qf1, kf0, kf1;
    {
        const f16x8 wfa = *(const f16x8*)&s_wa[(w * 32 + col) * 40 + s_ * 8];       // k 0-15
        const f16x8 wfb = *(const f16x8*)&s_wa[(w * 32 + col) * 40 + 16 + s_ * 8];  // k 16-31
        #pragma unroll
        for (int tile = 0; tile < 2; ++tile) {
            const int tok = tile * 32 + col;
            const f16x8 xb0 = *(const f16x8*)&s_x16[tok * 40 + s_ * 8];
            const f16x8 xb1 = *(const f16x8*)&s_x16[tok * 40 + 16 + s_ * 8];
            f32x16 C;
            #pragma unroll
            for (int r = 0; r < 16; ++r) C[r] = 0.f;
            C = __builtin_amdgcn_mfma_f32_32x32x16_f16(wfa, xb0, C, 0, 0, 0);
            C = __builtin_amdgcn_mfma_f32_32x32x16_f16(wfb, xb1, C, 0, 0, 0);
            // s0: regs0-3=q0-3, 4-7=k0-3, 8-11=v0-3 ; s1: regs0-3=q4-6+junk, etc.
            const unsigned qA = pkrtz(C[0], C[1]);              // s0:q01  s1:q45
            const unsigned qB = pkrtz(C[2], s_ ? 0.f : C[3]);   // s0:q23  s1:q6,0
            const unsigned kA = pkrtz(C[4], C[5]);              // s0:k01  s1:k45
            const unsigned kB = pkrtz(C[6], s_ ? 0.f : C[7]);   // s0:k23  s1:k6,0
            const unsigned qAx = (unsigned)__shfl_xor((int)qA, 32);
            const unsigned qBx = (unsigned)__shfl_xor((int)qB, 32);
            const unsigned kAx = (unsigned)__shfl_xor((int)kA, 32);
            const unsigned kBx = (unsigned)__shfl_xor((int)kB, 32);
            u32x4 qf, kf;
            qf.x = s_ ? 0u : qA;  qf.y = s_ ? 0u : qB;
            qf.z = s_ ? 0u : qAx; qf.w = s_ ? 0u : qBx;
            kf.x = s_ ? 0u : kA;  kf.y = s_ ? 0u : kB;
            kf.z = s_ ? 0u : kAx; kf.w = s_ ? 0u : kBx;
            #pragma unroll
            for (int j = 0; j < 4; ++j) {
                const int d = 4 * s_ + j;
                if (d < 7) {
                    const unsigned hv = pkrtz(C[8 + j], 0.f);
                    s_vt[w * 512 + ((d * 64 + tok) ^ (d << 3))] = (short)(hv & 0xffff);
                }
            }
            if (tile == 0) { qf0 = qf; kf0 = kf; } else { qf1 = qf; kf1 = kf; }
        }
    }
    __syncthreads();   // required: s_o16 (written in P2) aliases s_x16 (read in P1)

    // ---------------- P2: attention via MFMA (S^T = K·Q^T, O^T = V^T·P^T) ----------------
    {
        const int vr = min(8, HW - r0), vc = min(8, HW - c0);
        const bool edge = (vr < 8) || (vc < 8);
        const int dd = (col < 7) ? col : 6;   // V^T row (clamped; rows 7-31 unused)
        const f16x8 kfa = as_f16x8(kf0), kfb = as_f16x8(kf1);

        #pragma unroll
        for (int qt = 0; qt < 2; ++qt) {
            const f16x8 qfrag = as_f16x8(qt == 0 ? qf0 : qf1);
            f32x16 a0, a1;
            #pragma unroll
            for (int r = 0; r < 16; ++r) { a0[r] = 0.f; a1[r] = 0.f; }
            a0 = __builtin_amdgcn_mfma_f32_32x32x16_f16(kfa, qfrag, a0, 0, 0, 0);
            a1 = __builtin_amdgcn_mfma_f32_32x32x16_f16(kfb, qfrag, a1, 0, 0, 0);
            if (edge) {
                #pragma unroll
                for (int r = 0; r < 16; ++r) {
                    const int kc  = (r & 3) + 4 * s_;
                    const int kr0 = (r >> 2), kr1 = 4 + (r >> 2);
                    a0[r] = (kr0 < vr && kc < vc) ? a0[r] : -1e30f;
                    a1[r] = (kr1 < vr && kc < vc) ? a1[r] : -1e30f;
                }
            }
            float m = -1e30f;
            #pragma unroll
            for (int r = 0; r < 16; ++r) { m = fmaxf(m, a0[r]); m = fmaxf(m, a1[r]); }
            m = fmaxf(m, __shfl_xor(m, 32));
            float sum = 0.f;
            #pragma unroll
            for (int r = 0; r < 16; ++r) {
                a0[r] = __builtin_amdgcn_exp2f(a0[r] - m); sum += a0[r];
                a1[r] = __builtin_amdgcn_exp2f(a1[r] - m); sum += a1[r];
            }
            sum += __shfl_xor(sum, 32);
            const float inv = __builtin_amdgcn_rcpf(sum);

            f32x16 O;
            #pragma unroll
            for (int r = 0; r < 16; ++r) O[r] = 0.f;
            #pragma unroll
            for (int tt = 0; tt < 4; ++tt) {
                const f16x8 vfrag = *(const f16x8*)&s_vt[w * 512 + ((dd * 64 + 16 * tt + 8 * s_) ^ (dd << 3))];
                const int bb = 8 * (tt & 1);
                float p0,p1,p2,p3,p4,p5,p6,p7;
                if (tt < 2) { p0=a0[bb+0];p1=a0[bb+1];p2=a0[bb+2];p3=a0[bb+3];
                              p4=a0[bb+4];p5=a0[bb+5];p6=a0[bb+6];p7=a0[bb+7]; }
                else        { p0=a1[bb+0];p1=a1[bb+1];p2=a1[bb+2];p3=a1[bb+3];
                              p4=a1[bb+4];p5=a1[bb+5];p6=a1[bb+6];p7=a1[bb+7]; }
                const unsigned X0 = pkrtz(p0, p1), X1 = pkrtz(p2, p3);
                const unsigned Y0 = pkrtz(p4, p5), Y1 = pkrtz(p6, p7);
                const unsigned sX0 = (unsigned)__shfl_xor((int)X0, 32);
                const unsigned sX1 = (unsigned)__shfl_xor((int)X1, 32);
                const unsigned sY0 = (unsigned)__shfl_xor((int)Y0, 32);
                const unsigned sY1 = (unsigned)__shfl_xor((int)Y1, 32);
                u32x4 pf;
                pf.x = s_ ? sY0 : X0;
                pf.y = s_ ? sY1 : X1;
                pf.z = s_ ? Y0  : sX0;
                pf.w = s_ ? Y1  : sX1;
                O = __builtin_amdgcn_mfma_f32_32x32x16_f16(vfrag, as_f16x8(pf), O, 0, 0, 0);
            }
            // store attn out f16 into alias: s_o16[tok][c], c = w*7+d, d = r+4s_ (d=7 dead)
            // rows keep slot28=1.0, 29-31=0 from P0 -> k-slots 28-31 deterministic, W side zero there
            #pragma unroll
            for (int r = 0; r < 4; ++r) {
                const int d = r + 4 * s_;
                if (d < 7) {
                    const unsigned hv = pkrtz(O[r] * inv, 0.f);
                    s_o16[(32 * qt + col) * 40 + w * 7 + d] = (short)(hv & 0xffff);
                }
            }
        }
    }
    __syncthreads();

    // ---------------- P3: output projection via MFMA + cropped float4 writes ----------------
    {
        const int tile = w & 1, ch = w >> 1;   // token tile, co-half
        const int tok  = tile * 32 + col;
        const f16x8 ob0 = *(const f16x8*)&s_o16[tok * 40 + 8 * s_];        // k 0-15
        const f16x8 ob1 = *(const f16x8*)&s_o16[tok * 40 + 16 + 8 * s_];   // k 16-31
        const f16x8 wa0 = *(const f16x8*)&s_pw16[col * 40 + 8 * s_];       // A row = co = col
        const f16x8 wa1 = *(const f16x8*)&s_pw16[col * 40 + 16 + 8 * s_];
        f32x16 C;
        #pragma unroll
        for (int r = 0; r < 16; ++r) C[r] = 0.f;
        C = __builtin_amdgcn_mfma_f32_32x32x16_f16(wa0, ob0, C, 0, 0, 0);
        C = __builtin_amdgcn_mfma_f32_32x32x16_f16(wa1, ob1, C, 0, 0, 0);
        // C reg r -> co = (r&3) + 8*(r>>2) + 4s_, column = tok
        const int rr = r0 + (tok >> 3), cc = c0 + (tok & 7);
        if (rr < HW && cc < HW) {
            float* dst = &out[((b * HW + rr) * HW + cc) * 28];
            #pragma unroll
            for (int j2 = 0; j2 < 2; ++j2) {
                const int j  = 2 * ch + j2;
                const int co = 8 * j + 4 * s_;
                if (co < 28) {
                    const float4 bias = *(const float4*)&s_pb[co];
                    float4 o;
                    o.x = C[4*j+0] + bias.x; o.y = C[4*j+1] + bias.y;
                    o.z = C[4*j+2] + bias.z; o.w = C[4*j+3] + bias.w;
                    *(float4*)&dst[co] = o;
                }
            }
        }
    }
}

extern "C" void kernel_launch(void* const* d_in, const int* in_sizes, int n_in,
                              void* d_out, int out_size, void* d_ws, size_t ws_size,
                              hipStream_t stream) {
    const float* x      = (const float*)d_in[0];
    const float* qkv_w  = (const float*)d_in[1];
    const float* qkv_b  = (const float*)d_in[2];
    const float* proj_w = (const float*)d_in[3];
    const float* proj_b = (const float*)d_in[4];
    // inputs 5..18 (DynamicPosBias MLP): PDIM==1 makes every layernorm collapse to
    // its bias -> the bias table is a per-head constant -> cancelled by softmax.
    float* out = (float*)d_out;

    dim3 grid(8 * 32 * 32);
    dim3 block(256);
    hipLaunchKernelGGL(win_attn, grid, block, 0, stream,
                       x, qkv_w, qkv_b, proj_w, proj_b, out);
}